// Round 11
// baseline (78.055 us; speedup 1.0000x reference)
//
#include <hip/hip_runtime.h>
#include <hip/hip_fp16.h>

// Sizes (fixed):
// pc1_0: [8,2048,3] -> 16384 pts   d_in[0]
// pc1_1: [8, 512,3] ->  4096 pts   d_in[1]
// pc1_3: [8, 256,1] ->  2048 vals  d_in[2]
// pc2  : [8,2048,3] -> 16384 pts   d_in[3]
// pc3  : [8, 256,3] ->  2048 pts   d_in[4]
//
// ws layout (floats):
//   [0      ,16384) minA0 : pc1_0 -> pc2   (cd, a->b)
//   [16384  ,32768) minB0 : pc2   -> pc1_0 (cd, b->a)
//   [32768  ,36864) minA1 : pc1_1 -> pc2   (seed, a->b)
//   [36864  ,53248) minB1 : pc2   -> pc1_1 (seed, b->a)
//   [53248  ,55296) minC  : pc3[b] -> pc2[b] (confidence, full f32)
//   [55296  ,55304) acc[8]
//   [55304]         ticket

#define N_MINS 55296
#define R 8  // A-points per thread (A-chunk = 2048)

__device__ __forceinline__ float blockReduceSum(float v, float* sbuf) {
#pragma unroll
  for (int off = 32; off > 0; off >>= 1) v += __shfl_down(v, off, 64);
  int lane = threadIdx.x & 63;
  int wid  = threadIdx.x >> 6;
  if (lane == 0) sbuf[wid] = v;
  __syncthreads();
  float r = 0.f;
  if (threadIdx.x == 0) r = sbuf[0] + sbuf[1] + sbuf[2] + sbuf[3];
  return r;
}

// Fused NN-min kernel. All packed-f16 math forced via inline asm:
// per A-point per 2 B-points: 3x v_pk_fma_f16 + 1x v_pk_min_f16 = 2 VALU/pair.
// Stage-split over r for 8-way ILP (independent dep chains).
// d2 = ra + (w - 2 a.b); ra (|a|^2) kept f32, folded after the min.
// Confidence job stays f32 (feeds exp).
// LDS: tile4[p] = 16B = {(-2x0,-2x1),(-2y0,-2y1),(-2z0,-2z1),(w0,w1)} half2s
// stored as float bit-patterns. 64 entries = 128-point B slice.
__global__ __launch_bounds__(256) void k_nn_all(
    const float* __restrict__ pc10, const float* __restrict__ pc11,
    const float* __restrict__ pc2, const float* __restrict__ pc3,
    float* __restrict__ ws) {
  const int tid = threadIdx.x;
  const int blk = blockIdx.x;
  __shared__ float4 tile4[256];

  if (blk >= 2560) {  // confidence job: per-batch NN pc3[b] -> pc2[b], f32
    int j = blk - 2560;
    int b = j >> 3;
    int s = j & 7;
    int bi = b * 2048 + s * 256 + tid;
    {
      float bx = pc2[bi * 3 + 0], by = pc2[bi * 3 + 1], bz = pc2[bi * 3 + 2];
      tile4[tid] = make_float4(-2.f * bx, -2.f * by, -2.f * bz,
                               bx * bx + by * by + bz * bz);
    }
    int i = b * 256 + tid;
    float ax = pc3[i * 3 + 0], ay = pc3[i * 3 + 1], az = pc3[i * 3 + 2];
    float ra = ax * ax + ay * ay + az * az;
    __syncthreads();
    float mn = 3.0e38f;
#pragma unroll 4
    for (int t = 0; t < 256; ++t) {
      float4 q = tile4[t];
      float v = fmaf(q.x, ax, fmaf(q.y, ay, fmaf(q.z, az, q.w)));
      mn = fminf(mn, v);
    }
    atomicMin((unsigned int*)(ws + 53248 + i), __float_as_uint(fmaxf(mn + ra, 0.f)));
    return;
  }

  const float* A;
  const float* B;
  float* outMin;
  int aBase, bBase;
  if (blk < 1024) {           // job1: pc1_0 (16384) -> pc2 (16384)
    A = pc10; B = pc2; outMin = ws + 0;
    aBase = (blk >> 7) * 2048; bBase = (blk & 127) * 128;
  } else if (blk < 2048) {    // job2: pc2 (16384) -> pc1_0 (16384)
    int j = blk - 1024;
    A = pc2; B = pc10; outMin = ws + 16384;
    aBase = (j >> 7) * 2048; bBase = (j & 127) * 128;
  } else if (blk < 2304) {    // job3: pc1_1 (4096) -> pc2 (16384)
    int j = blk - 2048;
    A = pc11; B = pc2; outMin = ws + 32768;
    aBase = (j >> 7) * 2048; bBase = (j & 127) * 128;
  } else {                    // job4: pc2 (16384) -> pc1_1 (4096)
    int j = blk - 2304;
    A = pc2; B = pc11; outMin = ws + 36864;
    aBase = (j >> 5) * 2048; bBase = (j & 31) * 128;
  }

  // stage 128-point B slice as 64 fp16 pair-entries
  if (tid < 64) {
    int bi0 = (bBase + 2 * tid) * 3;
    float x0 = B[bi0 + 0], y0 = B[bi0 + 1], z0 = B[bi0 + 2];
    float x1 = B[bi0 + 3], y1 = B[bi0 + 4], z1 = B[bi0 + 5];
    float4 e;
    e.x = __builtin_bit_cast(float, __floats2half2_rn(-2.f * x0, -2.f * x1));
    e.y = __builtin_bit_cast(float, __floats2half2_rn(-2.f * y0, -2.f * y1));
    e.z = __builtin_bit_cast(float, __floats2half2_rn(-2.f * z0, -2.f * z1));
    e.w = __builtin_bit_cast(float, __floats2half2_rn(x0 * x0 + y0 * y0 + z0 * z0,
                                                      x1 * x1 + y1 * y1 + z1 * z1));
    tile4[tid] = e;
  }

  float ax2[R], ay2[R], az2[R];  // duplicated half2 bit-patterns
  float mn2[R];                  // running half2 minima bit-patterns
  float ra[R];
#pragma unroll
  for (int r = 0; r < R; ++r) {
    int ai = aBase + r * 256 + tid;
    float ax = A[ai * 3 + 0];
    float ay = A[ai * 3 + 1];
    float az = A[ai * 3 + 2];
    ax2[r] = __builtin_bit_cast(float, __float2half2_rn(ax));
    ay2[r] = __builtin_bit_cast(float, __float2half2_rn(ay));
    az2[r] = __builtin_bit_cast(float, __float2half2_rn(az));
    ra[r] = fmaf(ax, ax, fmaf(ay, ay, az * az));
    mn2[r] = __builtin_bit_cast(float, 0x7BFF7BFFu);  // (65504, 65504)
  }
  __syncthreads();

#pragma unroll 2
  for (int p = 0; p < 64; ++p) {
    float4 q = tile4[p];
    float t[R];
#pragma unroll
    for (int r = 0; r < R; ++r)
      asm("v_pk_fma_f16 %0, %1, %2, %3"
          : "=v"(t[r]) : "v"(q.z), "v"(az2[r]), "v"(q.w));
#pragma unroll
    for (int r = 0; r < R; ++r)
      asm("v_pk_fma_f16 %0, %1, %2, %0"
          : "+v"(t[r]) : "v"(q.y), "v"(ay2[r]));
#pragma unroll
    for (int r = 0; r < R; ++r)
      asm("v_pk_fma_f16 %0, %1, %2, %0"
          : "+v"(t[r]) : "v"(q.x), "v"(ax2[r]));
#pragma unroll
    for (int r = 0; r < R; ++r)
      asm("v_pk_min_f16 %0, %0, %1"
          : "+v"(mn2[r]) : "v"(t[r]));
  }

#pragma unroll
  for (int r = 0; r < R; ++r) {
    int ai = aBase + r * 256 + tid;
    __half2 m = __builtin_bit_cast(__half2, mn2[r]);
    float mnf = fminf(__low2float(m), __high2float(m));
    atomicMin((unsigned int*)(outMin + ai),
              __float_as_uint(fmaxf(mnf + ra[r], 0.f)));
  }
}

// Segmented reduce + final combine (ticket: last block writes out).
__global__ __launch_bounds__(256) void k_reduce(
    const float* __restrict__ ws, const float* __restrict__ pc13,
    const float* __restrict__ pc10, const float* __restrict__ pc2,
    float* __restrict__ acc, unsigned int* __restrict__ ticket,
    float* __restrict__ out) {
  __shared__ float sbuf[4];
  int idx = blockIdx.x * 256 + threadIdx.x;
  float v;
  int k;
  if (idx < 53248) {
    v = sqrtf(fmaxf(ws[idx], 0.f));
    k = (idx < 16384) ? 0 : (idx < 32768) ? 1 : (idx < 36864) ? 2 : 3;
  } else if (idx < 55296) {
    int i = idx - 53248;
    float score = expf(-sqrtf(fmaxf(ws[idx], 0.f)));
    float d = pc13[i] - score;
    v = d * d;
    k = 4;
  } else {
    int i = idx - 55296;
    float d = pc10[i] - pc2[i];
    v = d * d;
    k = 5;
  }
  float s = blockReduceSum(v, sbuf);
  if (threadIdx.x == 0) {
    atomicAdd(acc + k, s);
    __threadfence();
    unsigned int t = atomicAdd(ticket, 1u);
    if (t == gridDim.x - 1) {
      __threadfence();
      float cd   = (acc[0] + acc[1]) * (1.f / 16384.f);
      float seed = acc[2] * (1.f / 4096.f) + acc[3] * (1.f / 16384.f);
      float conf = acc[4] * (1.f / 2048.f);
      float p2p  = acc[5] * (1.f / 49152.f);
      out[0] = 0.5f * cd + 0.5f * seed + 0.5f * conf + p2p;
    }
  }
}

extern "C" void kernel_launch(void* const* d_in, const int* in_sizes, int n_in,
                              void* d_out, int out_size, void* d_ws, size_t ws_size,
                              hipStream_t stream) {
  const float* pc10 = (const float*)d_in[0];
  const float* pc11 = (const float*)d_in[1];
  const float* pc13 = (const float*)d_in[2];
  const float* pc2  = (const float*)d_in[3];
  const float* pc3  = (const float*)d_in[4];
  float* ws  = (float*)d_ws;
  float* acc = ws + N_MINS;
  float* out = (float*)d_out;

  // init: min arrays to ~3.39e38 (0x7F7F7F7F); acc[8]+ticket to 0
  (void)hipMemsetAsync(ws, 0x7F, N_MINS * sizeof(float), stream);
  (void)hipMemsetAsync(acc, 0, 9 * sizeof(float), stream);

  k_nn_all<<<2624, 256, 0, stream>>>(pc10, pc11, pc2, pc3, ws);

  int reduce_blocks = (N_MINS + 49152) / 256;  // 408
  k_reduce<<<reduce_blocks, 256, 0, stream>>>(ws, pc13, pc10, pc2, acc,
                                              (unsigned int*)(ws + 55304), out);
}